// Round 1
// baseline (501.962 us; speedup 1.0000x reference)
//
#include <hip/hip_runtime.h>
#include <hip/hip_bf16.h>

// Problem constants (fixed by the reference):
//   E = 1,000,000 edges, N = 50,000 nodes, D = 16, OUT = 64, FDIM = 256.
// Output P is [1, 64] fp32.

#define NNODES 50000

// ---------------------------------------------------------------------------
// k_prep: M[i][j] = (w @ Wc)[i] * alphaC[j]   (16x16, flat 256 floats)
// ---------------------------------------------------------------------------
__global__ void k_prep(const float* __restrict__ Wc,      // [64][16]
                       const float* __restrict__ alphaC,  // [16]
                       const float* __restrict__ w,       // [64]
                       float* __restrict__ M) {           // [256] out
    __shared__ float wWc[16];
    int t = threadIdx.x;  // 256 threads
    if (t < 16) {
        float s = 0.f;
        for (int o = 0; o < 64; ++o) s += w[o] * Wc[o * 16 + t];
        wWc[t] = s;
    }
    __syncthreads();
    M[t] = wWc[t >> 4] * alphaC[t & 15];
}

// ---------------------------------------------------------------------------
// k_logits: one wave per edge.  logits[dst[e]] += Sij[e] * dot(M, Cijj[e])
// lane i loads float4 at element offset i*4 of the 256-element edge matrix.
// ---------------------------------------------------------------------------
__global__ void k_logits(const float* __restrict__ Sij,
                         const float4* __restrict__ C,   // Cijj as float4
                         const int* __restrict__ dst,
                         const float* __restrict__ M,
                         float* __restrict__ logits,     // [NNODES], pre-zeroed
                         int E) {
    int t = blockIdx.x * blockDim.x + threadIdx.x;
    int lane  = t & 63;
    int gwid  = t >> 6;
    int waves = (gridDim.x * blockDim.x) >> 6;
    float4 m = reinterpret_cast<const float4*>(M)[lane];  // L1/L2 broadcast
    for (int e = gwid; e < E; e += waves) {
        float4 c = C[(size_t)e * 64 + lane];
        float d = fmaf(c.x, m.x, fmaf(c.y, m.y, fmaf(c.z, m.z, c.w * m.w)));
        #pragma unroll
        for (int off = 32; off; off >>= 1) d += __shfl_down(d, off, 64);
        if (lane == 0) atomicAdd(&logits[dst[e]], Sij[e] * d);
    }
}

// ---------------------------------------------------------------------------
// k_softmax: single block, att = softmax(logits) over NNODES entries.
// ---------------------------------------------------------------------------
__global__ void k_softmax(const float* __restrict__ logits,
                          float* __restrict__ att, int N) {
    __shared__ float red[16];
    __shared__ float bval;
    int t = threadIdx.x;          // 1024 threads
    int nt = blockDim.x;
    int nw = nt >> 6;

    float mx = -1e30f;
    for (int i = t; i < N; i += nt) mx = fmaxf(mx, logits[i]);
    #pragma unroll
    for (int off = 32; off; off >>= 1) mx = fmaxf(mx, __shfl_down(mx, off, 64));
    if ((t & 63) == 0) red[t >> 6] = mx;
    __syncthreads();
    if (t == 0) {
        float m = red[0];
        for (int i = 1; i < nw; ++i) m = fmaxf(m, red[i]);
        bval = m;
    }
    __syncthreads();
    float m = bval;

    float s = 0.f;
    for (int i = t; i < N; i += nt) {
        float e = __expf(logits[i] - m);
        att[i] = e;
        s += e;
    }
    #pragma unroll
    for (int off = 32; off; off >>= 1) s += __shfl_down(s, off, 64);
    __syncthreads();               // ensure everyone done reading bval (max)
    if ((t & 63) == 0) red[t >> 6] = s;
    __syncthreads();
    if (t == 0) {
        float ss = 0.f;
        for (int i = 0; i < nw; ++i) ss += red[i];
        bval = ss;
    }
    __syncthreads();
    float inv = 1.f / bval;
    for (int i = t; i < N; i += nt) att[i] *= inv;
}

// ---------------------------------------------------------------------------
// k_ci: Ci[256] += sum_e att[dst[e]]*Sij[e]*Cijj[e].  One wave per edge,
// per-lane float4 register accumulator, block reduce in LDS, 256 global
// atomics per block.
// ---------------------------------------------------------------------------
__global__ void k_ci(const float* __restrict__ Sij,
                     const float4* __restrict__ C,
                     const int* __restrict__ dst,
                     const float* __restrict__ att,
                     float* __restrict__ Ci,   // [256], pre-zeroed
                     int E) {
    int t = threadIdx.x;           // 256 threads = 4 waves
    int lane = t & 63;
    int wid  = t >> 6;
    int gwid  = (blockIdx.x * blockDim.x + t) >> 6;
    int waves = (gridDim.x * blockDim.x) >> 6;

    float4 acc = make_float4(0.f, 0.f, 0.f, 0.f);
    for (int e = gwid; e < E; e += waves) {
        float wgt = att[dst[e]] * Sij[e];       // broadcast loads
        float4 c = C[(size_t)e * 64 + lane];
        acc.x = fmaf(wgt, c.x, acc.x);
        acc.y = fmaf(wgt, c.y, acc.y);
        acc.z = fmaf(wgt, c.z, acc.z);
        acc.w = fmaf(wgt, c.w, acc.w);
    }
    __shared__ float part[4][256];
    reinterpret_cast<float4*>(part[wid])[lane] = acc;
    __syncthreads();
    float s = part[0][t] + part[1][t] + part[2][t] + part[3][t];
    atomicAdd(&Ci[t], s);
}

// ---------------------------------------------------------------------------
// k_tail: the tiny MLP head.  256 threads, one block.
//   Fi[i][f]  = sigmoid(relu(sum_j Ci[i][j]*W1[f][j] + b1[f]))
//   Fi2[f]    = relu(sum_i Fi[i][f]*W2[i] + b2)
//   P[o]      = sum_f Wf[o][f]*Fi2[f] + bias[o]
// ---------------------------------------------------------------------------
__global__ void k_tail(const float* __restrict__ Ci,    // [256]
                       const float* __restrict__ W1,    // [256][16]
                       const float* __restrict__ b1,    // [256]
                       const float* __restrict__ W2,    // [16]
                       const float* __restrict__ b2,    // [1]
                       const float* __restrict__ Wf,    // [64][256]
                       const float* __restrict__ bias,  // [64]
                       float* __restrict__ out) {       // [64]
    __shared__ float ci[256];
    __shared__ float fi2[256];
    int t = threadIdx.x;  // 256
    ci[t] = Ci[t];
    __syncthreads();

    float w1row[16];
    #pragma unroll
    for (int j = 0; j < 16; ++j) w1row[j] = W1[t * 16 + j];
    float bb = b1[t];
    float g = 0.f;
    #pragma unroll
    for (int i = 0; i < 16; ++i) {
        float s = bb;
        #pragma unroll
        for (int j = 0; j < 16; ++j) s = fmaf(ci[i * 16 + j], w1row[j], s);
        s = fmaxf(s, 0.f);                       // relu
        float sg = 1.f / (1.f + __expf(-s));     // sigmoid
        g = fmaf(sg, W2[i], g);
    }
    fi2[t] = fmaxf(g + b2[0], 0.f);
    __syncthreads();

    if (t < 64) {
        float s = bias[t];
        for (int f = 0; f < 256; ++f) s = fmaf(Wf[t * 256 + f], fi2[f], s);
        out[t] = s;
    }
}

// ---------------------------------------------------------------------------
extern "C" void kernel_launch(void* const* d_in, const int* in_sizes, int n_in,
                              void* d_out, int out_size, void* d_ws, size_t ws_size,
                              hipStream_t stream) {
    const float* Sij    = (const float*)d_in[0];
    const float* Cijj   = (const float*)d_in[1];
    const int*   dst    = (const int*)d_in[2];
    // d_in[3] = N (device scalar; value is fixed at 50000 for this problem)
    const float* Wc     = (const float*)d_in[4];
    const float* alphaC = (const float*)d_in[5];
    // d_in[6] = alphaf, d_in[7] = b : contribute a node-independent constant
    // to every logit -> softmax-invariant -> unused.
    const float* w_     = (const float*)d_in[8];
    const float* Wf     = (const float*)d_in[9];
    const float* bias   = (const float*)d_in[10];
    const float* W1     = (const float*)d_in[11];
    const float* b1     = (const float*)d_in[12];
    const float* W2     = (const float*)d_in[13];
    const float* b2     = (const float*)d_in[14];

    const int E = in_sizes[0];
    const int N = NNODES;

    // Workspace layout (floats): logits[N] | att[N] | M[256] | Ci[256]
    float* logits = (float*)d_ws;
    float* att    = logits + N;
    float* M      = att + N;
    float* Ci     = M + 256;

    hipMemsetAsync(logits, 0, N * sizeof(float), stream);
    hipMemsetAsync(Ci, 0, 256 * sizeof(float), stream);

    k_prep<<<1, 256, 0, stream>>>(Wc, alphaC, w_, M);
    k_logits<<<2048, 256, 0, stream>>>(Sij, (const float4*)Cijj, dst, M, logits, E);
    k_softmax<<<1, 1024, 0, stream>>>(logits, att, N);
    k_ci<<<2048, 256, 0, stream>>>(Sij, (const float4*)Cijj, dst, att, Ci, E);
    k_tail<<<1, 256, 0, stream>>>(Ci, W1, b1, W2, b2, Wf, bias, (float*)d_out);
}

// Round 2
// 383.778 us; speedup vs baseline: 1.3079x; 1.3079x over previous
//
#include <hip/hip_runtime.h>
#include <hip/hip_bf16.h>

// Problem constants (fixed by the reference):
//   E = 1,000,000 edges, N = 50,000 nodes, D = 16, OUT = 64, FDIM = 256.
// Output P is [1, 64] fp32.
//
// Algebra used:
//   logits_n = sum_{ij} corr_n[ij] * M[ij],  M = outer(w@Wc, alphaC)
//   (the Wf@alphaf+b term is node-independent -> softmax-invariant -> dropped)
//   corr never materialized:  logits[dst[e]] += Sij[e] * dot(M, Cijj[e])
//   Ci = sum_e att[dst[e]] * Sij[e] * Cijj[e]
// -> two streaming passes over the 1.024 GB Cijj tensor = the structural floor.

#define NNODES 50000

typedef float f32x4 __attribute__((ext_vector_type(4)));

// ---------------------------------------------------------------------------
// k_init: zero logits[N] and Ci[256]; compute M[i][j] = (w@Wc)[i]*alphaC[j].
// ---------------------------------------------------------------------------
__global__ void k_init(const float* __restrict__ Wc,      // [64][16]
                       const float* __restrict__ alphaC,  // [16]
                       const float* __restrict__ w,       // [64]
                       float* __restrict__ M,             // [256]
                       float* __restrict__ logits,        // [N]
                       float* __restrict__ Ci,            // [256]
                       int N) {
    int t = blockIdx.x * blockDim.x + threadIdx.x;
    int stride = gridDim.x * blockDim.x;
    for (int i = t; i < N; i += stride) logits[i] = 0.f;
    if (blockIdx.x == 0) {
        __shared__ float wWc[16];
        int tt = threadIdx.x;  // 256
        if (tt < 16) {
            float s = 0.f;
            for (int o = 0; o < 64; ++o) s = fmaf(w[o], Wc[o * 16 + tt], s);
            wWc[tt] = s;
        }
        __syncthreads();
        M[tt]  = wWc[tt >> 4] * alphaC[tt & 15];
        Ci[tt] = 0.f;
    }
}

// ---------------------------------------------------------------------------
// k_logits: 16 lanes per edge, 4 edges per wave, 4 float4 loads per lane.
// logits[dst[e]] += Sij[e] * dot(M, Cijj[e])
// Lane layout: sub = lane>>4 (edge in quad), eoff = lane&15 (float4 column).
// Lane loads C[e*64 + j*16 + eoff] for j=0..3 -> 16 elements per lane.
// ---------------------------------------------------------------------------
__global__ void k_logits(const float* __restrict__ Sij,
                         const f32x4* __restrict__ C,
                         const int* __restrict__ dst,
                         const float* __restrict__ M,
                         float* __restrict__ logits,
                         int E) {
    int t = blockIdx.x * blockDim.x + threadIdx.x;
    int lane = t & 63;
    int sub  = lane >> 4;
    int eoff = lane & 15;
    int gwid  = t >> 6;
    int waves = (gridDim.x * blockDim.x) >> 6;

    const f32x4* M4 = reinterpret_cast<const f32x4*>(M);
    f32x4 m0 = M4[eoff], m1 = M4[16 + eoff], m2 = M4[32 + eoff], m3 = M4[48 + eoff];

    int nq = (E + 3) >> 2;
    for (int q = gwid; q < nq; q += waves) {
        int e = (q << 2) + sub;
        float d = 0.f;
        if (e < E) {
            size_t base = (size_t)e * 64 + eoff;
            f32x4 c0 = __builtin_nontemporal_load(C + base);
            f32x4 c1 = __builtin_nontemporal_load(C + base + 16);
            f32x4 c2 = __builtin_nontemporal_load(C + base + 32);
            f32x4 c3 = __builtin_nontemporal_load(C + base + 48);
            d = c0[0]*m0[0] + c0[1]*m0[1] + c0[2]*m0[2] + c0[3]*m0[3];
            d = fmaf(c1[0], m1[0], fmaf(c1[1], m1[1], fmaf(c1[2], m1[2], fmaf(c1[3], m1[3], d))));
            d = fmaf(c2[0], m2[0], fmaf(c2[1], m2[1], fmaf(c2[2], m2[2], fmaf(c2[3], m2[3], d))));
            d = fmaf(c3[0], m3[0], fmaf(c3[1], m3[1], fmaf(c3[2], m3[2], fmaf(c3[3], m3[3], d))));
        }
        #pragma unroll
        for (int off = 8; off; off >>= 1) d += __shfl_down(d, off, 16);
        if (eoff == 0 && e < E) atomicAdd(&logits[dst[e]], Sij[e] * d);
    }
}

// ---------------------------------------------------------------------------
// k_softmax: single block, att = softmax(logits) over NNODES entries.
// ---------------------------------------------------------------------------
__global__ void k_softmax(const float* __restrict__ logits,
                          float* __restrict__ att, int N) {
    __shared__ float red[16];
    __shared__ float bval;
    int t = threadIdx.x;          // 1024 threads
    int nt = blockDim.x;
    int nw = nt >> 6;

    float mx = -1e30f;
    for (int i = t; i < N; i += nt) mx = fmaxf(mx, logits[i]);
    #pragma unroll
    for (int off = 32; off; off >>= 1) mx = fmaxf(mx, __shfl_down(mx, off, 64));
    if ((t & 63) == 0) red[t >> 6] = mx;
    __syncthreads();
    if (t == 0) {
        float m = red[0];
        for (int i = 1; i < nw; ++i) m = fmaxf(m, red[i]);
        bval = m;
    }
    __syncthreads();
    float m = bval;

    float s = 0.f;
    for (int i = t; i < N; i += nt) {
        float e = __expf(logits[i] - m);
        att[i] = e;
        s += e;
    }
    #pragma unroll
    for (int off = 32; off; off >>= 1) s += __shfl_down(s, off, 64);
    __syncthreads();
    if ((t & 63) == 0) red[t >> 6] = s;
    __syncthreads();
    if (t == 0) {
        float ss = 0.f;
        for (int i = 0; i < nw; ++i) ss += red[i];
        bval = ss;
    }
    __syncthreads();
    float inv = 1.f / bval;
    for (int i = t; i < N; i += nt) att[i] *= inv;
}

// ---------------------------------------------------------------------------
// k_ci: Ci[256] += sum_e att[dst[e]]*Sij[e]*Cijj[e].
// Same 16-lanes-per-edge layout; per-lane f32x4 acc[4] (element (j*16+eoff)),
// LDS block reduce over {wave, sub}, 256 global atomics per block.
// ---------------------------------------------------------------------------
__global__ void k_ci(const float* __restrict__ Sij,
                     const f32x4* __restrict__ C,
                     const int* __restrict__ dst,
                     const float* __restrict__ att,
                     float* __restrict__ Ci,   // [256], pre-zeroed
                     int E) {
    int t = threadIdx.x;           // 256 threads = 4 waves
    int lane = t & 63;
    int sub  = lane >> 4;
    int eoff = lane & 15;
    int gwid  = (blockIdx.x * blockDim.x + t) >> 6;
    int waves = (gridDim.x * blockDim.x) >> 6;

    f32x4 a0 = 0.f, a1 = 0.f, a2 = 0.f, a3 = 0.f;
    int nq = (E + 3) >> 2;
    for (int q = gwid; q < nq; q += waves) {
        int e = (q << 2) + sub;
        if (e < E) {
            float wgt = att[dst[e]] * Sij[e];   // one cacheline per wave, broadcast
            size_t base = (size_t)e * 64 + eoff;
            f32x4 c0 = __builtin_nontemporal_load(C + base);
            f32x4 c1 = __builtin_nontemporal_load(C + base + 16);
            f32x4 c2 = __builtin_nontemporal_load(C + base + 32);
            f32x4 c3 = __builtin_nontemporal_load(C + base + 48);
            a0 += wgt * c0;
            a1 += wgt * c1;
            a2 += wgt * c2;
            a3 += wgt * c3;
        }
    }
    __shared__ f32x4 part[256][4];   // 16 KiB
    part[t][0] = a0;
    part[t][1] = a1;
    part[t][2] = a2;
    part[t][3] = a3;
    __syncthreads();
    // element index t: k = t&3, f4 = t>>2 (0..63), eo = f4&15, j = f4>>4
    int k  = t & 3;
    int f4 = t >> 2;
    int eo = f4 & 15;
    int j  = f4 >> 4;
    float s = 0.f;
    #pragma unroll
    for (int wv = 0; wv < 4; ++wv)
        #pragma unroll
        for (int sb = 0; sb < 4; ++sb)
            s += part[wv * 64 + sb * 16 + eo][j][k];
    atomicAdd(&Ci[t], s);
}

// ---------------------------------------------------------------------------
// k_tail: the tiny MLP head.  256 threads, one block.
// ---------------------------------------------------------------------------
__global__ void k_tail(const float* __restrict__ Ci,    // [256]
                       const float* __restrict__ W1,    // [256][16]
                       const float* __restrict__ b1,    // [256]
                       const float* __restrict__ W2,    // [16]
                       const float* __restrict__ b2,    // [1]
                       const float* __restrict__ Wf,    // [64][256]
                       const float* __restrict__ bias,  // [64]
                       float* __restrict__ out) {       // [64]
    __shared__ float ci[256];
    __shared__ float fi2[256];
    int t = threadIdx.x;  // 256
    ci[t] = Ci[t];
    __syncthreads();

    float w1row[16];
    #pragma unroll
    for (int j = 0; j < 16; ++j) w1row[j] = W1[t * 16 + j];
    float bb = b1[t];
    float g = 0.f;
    #pragma unroll
    for (int i = 0; i < 16; ++i) {
        float s = bb;
        #pragma unroll
        for (int j = 0; j < 16; ++j) s = fmaf(ci[i * 16 + j], w1row[j], s);
        s = fmaxf(s, 0.f);                       // relu
        float sg = 1.f / (1.f + __expf(-s));     // sigmoid
        g = fmaf(sg, W2[i], g);
    }
    fi2[t] = fmaxf(g + b2[0], 0.f);
    __syncthreads();

    if (t < 64) {
        float s = bias[t];
        for (int f = 0; f < 256; ++f) s = fmaf(Wf[t * 256 + f], fi2[f], s);
        out[t] = s;
    }
}

// ---------------------------------------------------------------------------
extern "C" void kernel_launch(void* const* d_in, const int* in_sizes, int n_in,
                              void* d_out, int out_size, void* d_ws, size_t ws_size,
                              hipStream_t stream) {
    const float* Sij    = (const float*)d_in[0];
    const float* Cijj   = (const float*)d_in[1];
    const int*   dst    = (const int*)d_in[2];
    // d_in[3] = N (device scalar; fixed at 50000 for this problem)
    const float* Wc     = (const float*)d_in[4];
    const float* alphaC = (const float*)d_in[5];
    // d_in[6] = alphaf, d_in[7] = b : node-independent logit constant -> unused
    const float* w_     = (const float*)d_in[8];
    const float* Wf     = (const float*)d_in[9];
    const float* bias   = (const float*)d_in[10];
    const float* W1     = (const float*)d_in[11];
    const float* b1     = (const float*)d_in[12];
    const float* W2     = (const float*)d_in[13];
    const float* b2     = (const float*)d_in[14];

    const int E = in_sizes[0];
    const int N = NNODES;

    // Workspace layout (floats): logits[N] | att[N] | M[256] | Ci[256]
    float* logits = (float*)d_ws;
    float* att    = logits + N;
    float* M      = att + N;
    float* Ci     = M + 256;

    k_init<<<64, 256, 0, stream>>>(Wc, alphaC, w_, M, logits, Ci, N);
    k_logits<<<2048, 256, 0, stream>>>(Sij, (const f32x4*)Cijj, dst, M, logits, E);
    k_softmax<<<1, 1024, 0, stream>>>(logits, att, N);
    k_ci<<<1024, 256, 0, stream>>>(Sij, (const f32x4*)Cijj, dst, att, Ci, E);
    k_tail<<<1, 256, 0, stream>>>(Ci, W1, b1, W2, b2, Wf, bias, (float*)d_out);
}

// Round 3
// 372.279 us; speedup vs baseline: 1.3484x; 1.0309x over previous
//
#include <hip/hip_runtime.h>
#include <hip/hip_bf16.h>

// Problem constants (fixed by the reference):
//   E = 1,000,000 edges, N = 50,000 nodes, D = 16, OUT = 64, FDIM = 256.
// Output P is [1, 64] fp32.
//
// Algebra:
//   logits_n = sum_{ij} corr_n[ij] * M[ij],  M = outer(w@Wc, alphaC)
//   (Wf@alphaf+b term is node-independent -> softmax-invariant -> dropped)
//   logits[dst[e]] += Sij[e] * dot(M, Cijj[e])          (pass 1 over Cijj)
//   Ci = (1/Z) * sum_e exp(l[dst(e)]-m)*Sij[e]*Cijj[e]  (pass 2 over Cijj)
// Softmax normalization (1/Z) folded into the MLP tail (Ci is 256 floats).
// Pass 2 walks edges in REVERSE so pass 1's L3-resident tail (~256 MB) hits.

#define NNODES 50000

typedef float f32x4 __attribute__((ext_vector_type(4)));

// Monotonic float<->uint encoding for atomicMax on signed floats.
__device__ __forceinline__ unsigned f2o(float f) {
    unsigned u = __float_as_uint(f);
    return (u & 0x80000000u) ? ~u : (u | 0x80000000u);
}
__device__ __forceinline__ float o2f(unsigned u) {
    return (u & 0x80000000u) ? __uint_as_float(u ^ 0x80000000u)
                             : __uint_as_float(~u);
}

// ---------------------------------------------------------------------------
// k_init: zero logits[N], Ci[256], Z, mEnc; M[i][j] = (w@Wc)[i]*alphaC[j].
// ---------------------------------------------------------------------------
__global__ void k_init(const float* __restrict__ Wc,      // [64][16]
                       const float* __restrict__ alphaC,  // [16]
                       const float* __restrict__ w,       // [64]
                       float* __restrict__ M,             // [256]
                       float* __restrict__ logits,        // [N]
                       float* __restrict__ Ci,            // [256]
                       float* __restrict__ Z,             // [1]
                       unsigned* __restrict__ mEnc,       // [1]
                       int N) {
    int t = blockIdx.x * blockDim.x + threadIdx.x;
    int stride = gridDim.x * blockDim.x;
    for (int i = t; i < N; i += stride) logits[i] = 0.f;
    if (blockIdx.x == 0) {
        __shared__ float wWc[16];
        int tt = threadIdx.x;  // 256
        if (tt < 16) {
            float s = 0.f;
            for (int o = 0; o < 64; ++o) s = fmaf(w[o], Wc[o * 16 + tt], s);
            wWc[tt] = s;
        }
        __syncthreads();
        M[tt]  = wWc[tt >> 4] * alphaC[tt & 15];
        Ci[tt] = 0.f;
        if (tt == 0) { Z[0] = 0.f; mEnc[0] = 0u; }  // 0 < f2o(any finite)
    }
}

// ---------------------------------------------------------------------------
// k_logits: 16 lanes per edge, 4 edges per wave, 4 float4 loads per lane.
// Normal (caching) loads so the streamed tail stays resident in L3 for the
// reversed pass 2.
// ---------------------------------------------------------------------------
__global__ void k_logits(const float* __restrict__ Sij,
                         const f32x4* __restrict__ C,
                         const int* __restrict__ dst,
                         const float* __restrict__ M,
                         float* __restrict__ logits,
                         int E) {
    int t = blockIdx.x * blockDim.x + threadIdx.x;
    int lane = t & 63;
    int sub  = lane >> 4;
    int eoff = lane & 15;
    int gwid  = t >> 6;
    int waves = (gridDim.x * blockDim.x) >> 6;

    const f32x4* M4 = reinterpret_cast<const f32x4*>(M);
    f32x4 m0 = M4[eoff], m1 = M4[16 + eoff], m2 = M4[32 + eoff], m3 = M4[48 + eoff];

    int nq = (E + 3) >> 2;
    for (int q = gwid; q < nq; q += waves) {
        int e = (q << 2) + sub;
        float d = 0.f;
        if (e < E) {
            size_t base = (size_t)e * 64 + eoff;
            f32x4 c0 = C[base];
            f32x4 c1 = C[base + 16];
            f32x4 c2 = C[base + 32];
            f32x4 c3 = C[base + 48];
            d = c0[0]*m0[0] + c0[1]*m0[1] + c0[2]*m0[2] + c0[3]*m0[3];
            d = fmaf(c1[0], m1[0], fmaf(c1[1], m1[1], fmaf(c1[2], m1[2], fmaf(c1[3], m1[3], d))));
            d = fmaf(c2[0], m2[0], fmaf(c2[1], m2[1], fmaf(c2[2], m2[2], fmaf(c2[3], m2[3], d))));
            d = fmaf(c3[0], m3[0], fmaf(c3[1], m3[1], fmaf(c3[2], m3[2], fmaf(c3[3], m3[3], d))));
        }
        #pragma unroll
        for (int off = 8; off; off >>= 1) d += __shfl_down(d, off, 16);
        if (eoff == 0 && e < E) atomicAdd(&logits[dst[e]], Sij[e] * d);
    }
}

// ---------------------------------------------------------------------------
// k_max: global max of logits -> mEnc (monotonic-uint atomicMax).
// ---------------------------------------------------------------------------
__global__ void k_max(const float* __restrict__ logits,
                      unsigned* __restrict__ mEnc, int N) {
    __shared__ float red[4];
    int t = blockIdx.x * blockDim.x + threadIdx.x;
    int stride = gridDim.x * blockDim.x;
    float mx = -1e30f;
    for (int i = t; i < N; i += stride) mx = fmaxf(mx, logits[i]);
    #pragma unroll
    for (int off = 32; off; off >>= 1) mx = fmaxf(mx, __shfl_down(mx, off, 64));
    int lt = threadIdx.x;
    if ((lt & 63) == 0) red[lt >> 6] = mx;
    __syncthreads();
    if (lt == 0) {
        float m = red[0];
        for (int i = 1; i < (int)(blockDim.x >> 6); ++i) m = fmaxf(m, red[i]);
        atomicMax(mEnc, f2o(m));
    }
}

// ---------------------------------------------------------------------------
// k_exp: att[i] = exp(logits[i]-m); Z += sum (one atomicAdd per block).
// ---------------------------------------------------------------------------
__global__ void k_exp(const float* __restrict__ logits,
                      const unsigned* __restrict__ mEnc,
                      float* __restrict__ att,
                      float* __restrict__ Z, int N) {
    __shared__ float red[4];
    float m = o2f(*mEnc);
    int t = blockIdx.x * blockDim.x + threadIdx.x;
    int stride = gridDim.x * blockDim.x;
    float s = 0.f;
    for (int i = t; i < N; i += stride) {
        float e = __expf(logits[i] - m);
        att[i] = e;
        s += e;
    }
    #pragma unroll
    for (int off = 32; off; off >>= 1) s += __shfl_down(s, off, 64);
    int lt = threadIdx.x;
    if ((lt & 63) == 0) red[lt >> 6] = s;
    __syncthreads();
    if (lt == 0) {
        float ss = 0.f;
        for (int i = 0; i < (int)(blockDim.x >> 6); ++i) ss += red[i];
        atomicAdd(Z, ss);
    }
}

// ---------------------------------------------------------------------------
// k_ci: Ci[256] += sum_e att[dst[e]]*Sij[e]*Cijj[e]  (att = unnormalized exp).
// REVERSED edge order: first-touched edges are the last pass 1 streamed,
// still resident in the 256 MB Infinity Cache. Nontemporal (last use).
// ---------------------------------------------------------------------------
__global__ void k_ci(const float* __restrict__ Sij,
                     const f32x4* __restrict__ C,
                     const int* __restrict__ dst,
                     const float* __restrict__ att,
                     float* __restrict__ Ci,   // [256], pre-zeroed
                     int E) {
    int t = threadIdx.x;           // 256 threads = 4 waves
    int lane = t & 63;
    int sub  = lane >> 4;
    int eoff = lane & 15;
    int gwid  = (blockIdx.x * blockDim.x + t) >> 6;
    int waves = (gridDim.x * blockDim.x) >> 6;

    f32x4 a0 = 0.f, a1 = 0.f, a2 = 0.f, a3 = 0.f;
    int nq = (E + 3) >> 2;
    for (int q = gwid; q < nq; q += waves) {
        int qq = nq - 1 - q;               // reverse sweep
        int e = (qq << 2) + sub;
        if (e < E) {
            float wgt = att[dst[e]] * Sij[e];
            size_t base = (size_t)e * 64 + eoff;
            f32x4 c0 = __builtin_nontemporal_load(C + base);
            f32x4 c1 = __builtin_nontemporal_load(C + base + 16);
            f32x4 c2 = __builtin_nontemporal_load(C + base + 32);
            f32x4 c3 = __builtin_nontemporal_load(C + base + 48);
            a0 += wgt * c0;
            a1 += wgt * c1;
            a2 += wgt * c2;
            a3 += wgt * c3;
        }
    }
    __shared__ f32x4 part[256][4];   // 16 KiB
    part[t][0] = a0;
    part[t][1] = a1;
    part[t][2] = a2;
    part[t][3] = a3;
    __syncthreads();
    // element index t: k=t&3, f4=t>>2 (0..63), eo=f4&15, j=f4>>4
    int k  = t & 3;
    int f4 = t >> 2;
    int eo = f4 & 15;
    int j  = f4 >> 4;
    float s = 0.f;
    #pragma unroll
    for (int wv = 0; wv < 4; ++wv)
        #pragma unroll
        for (int sb = 0; sb < 4; ++sb)
            s += part[wv * 64 + sb * 16 + eo][j][k];
    atomicAdd(&Ci[t], s);
}

// ---------------------------------------------------------------------------
// k_tail: MLP head; Ci scaled by 1/Z here (deferred softmax normalization).
// ---------------------------------------------------------------------------
__global__ void k_tail(const float* __restrict__ Ci,    // [256] (unnormalized)
                       const float* __restrict__ Z,     // [1]
                       const float* __restrict__ W1,    // [256][16]
                       const float* __restrict__ b1,    // [256]
                       const float* __restrict__ W2,    // [16]
                       const float* __restrict__ b2,    // [1]
                       const float* __restrict__ Wf,    // [64][256]
                       const float* __restrict__ bias,  // [64]
                       float* __restrict__ out) {       // [64]
    __shared__ float ci[256];
    __shared__ float fi2[256];
    int t = threadIdx.x;  // 256
    float invZ = 1.f / Z[0];
    ci[t] = Ci[t] * invZ;
    __syncthreads();

    float w1row[16];
    #pragma unroll
    for (int j = 0; j < 16; ++j) w1row[j] = W1[t * 16 + j];
    float bb = b1[t];
    float g = 0.f;
    #pragma unroll
    for (int i = 0; i < 16; ++i) {
        float s = bb;
        #pragma unroll
        for (int j = 0; j < 16; ++j) s = fmaf(ci[i * 16 + j], w1row[j], s);
        s = fmaxf(s, 0.f);                       // relu
        float sg = 1.f / (1.f + __expf(-s));     // sigmoid
        g = fmaf(sg, W2[i], g);
    }
    fi2[t] = fmaxf(g + b2[0], 0.f);
    __syncthreads();

    if (t < 64) {
        float s = bias[t];
        for (int f = 0; f < 256; ++f) s = fmaf(Wf[t * 256 + f], fi2[f], s);
        out[t] = s;
    }
}

// ---------------------------------------------------------------------------
extern "C" void kernel_launch(void* const* d_in, const int* in_sizes, int n_in,
                              void* d_out, int out_size, void* d_ws, size_t ws_size,
                              hipStream_t stream) {
    const float* Sij    = (const float*)d_in[0];
    const float* Cijj   = (const float*)d_in[1];
    const int*   dst    = (const int*)d_in[2];
    // d_in[3] = N (device scalar; fixed at 50000 for this problem)
    const float* Wc     = (const float*)d_in[4];
    const float* alphaC = (const float*)d_in[5];
    // d_in[6] = alphaf, d_in[7] = b : node-independent logit constant -> unused
    const float* w_     = (const float*)d_in[8];
    const float* Wf     = (const float*)d_in[9];
    const float* bias   = (const float*)d_in[10];
    const float* W1     = (const float*)d_in[11];
    const float* b1     = (const float*)d_in[12];
    const float* W2     = (const float*)d_in[13];
    const float* b2     = (const float*)d_in[14];

    const int E = in_sizes[0];
    const int N = NNODES;

    // Workspace (floats): logits[N] | att[N] | M[256] | Ci[256] | Z[1] | mEnc[1]
    float* logits = (float*)d_ws;
    float* att    = logits + N;
    float* M      = att + N;
    float* Ci     = M + 256;
    float* Z      = Ci + 256;
    unsigned* mEnc = (unsigned*)(Z + 1);

    k_init<<<64, 256, 0, stream>>>(Wc, alphaC, w_, M, logits, Ci, Z, mEnc, N);
    k_logits<<<2048, 256, 0, stream>>>(Sij, (const f32x4*)Cijj, dst, M, logits, E);
    k_max<<<50, 256, 0, stream>>>(logits, mEnc, N);
    k_exp<<<50, 256, 0, stream>>>(logits, mEnc, att, Z, N);
    k_ci<<<2048, 256, 0, stream>>>(Sij, (const f32x4*)Cijj, dst, att, Ci, E);
    k_tail<<<1, 256, 0, stream>>>(Ci, Z, W1, b1, W2, b2, Wf, bias, (float*)d_out);
}

// Round 4
// 348.660 us; speedup vs baseline: 1.4397x; 1.0677x over previous
//
#include <hip/hip_runtime.h>
#include <hip/hip_bf16.h>

// Problem constants (fixed by the reference):
//   E = 1,000,000 edges, N = 50,000 nodes, D = 16, OUT = 64, FDIM = 256.
// Output P is [1, 64] fp32.
//
// Algebra:
//   logits_n = dot(M, corr_n),  M = outer(w@Wc, alphaC)
//   (Wf@alphaf+b term is node-independent -> softmax-invariant -> dropped)
//   corr_n = sum_{e: dst(e)=n} Sij[e]*Cijj[e]
//   Ci = (1/Z) * sum_n exp(logit_n - m) * corr_n
// Main path: bucketed CSR -> per-node gather materializes corr (51.2 MB)
// -> Cijj (1.024 GB) is read ONCE. 1/Z folded into the MLP tail.
// Fallback (small ws): two streaming passes over Cijj (round-3 scheme).

#define NNODES 50000
#define CAP 96   // max edges/node bucket; deg ~ Poisson(20), P(>96) < 1e-30

typedef float f32x4 __attribute__((ext_vector_type(4)));

// Monotonic float<->uint encoding for atomicMax on signed floats.
__device__ __forceinline__ unsigned f2o(float f) {
    unsigned u = __float_as_uint(f);
    return (u & 0x80000000u) ? ~u : (u | 0x80000000u);
}
__device__ __forceinline__ float o2f(unsigned u) {
    return (u & 0x80000000u) ? __uint_as_float(u ^ 0x80000000u)
                             : __uint_as_float(~u);
}

// ---------------------------------------------------------------------------
// Shared small kernels
// ---------------------------------------------------------------------------
__global__ void k_max(const float* __restrict__ logits,
                      unsigned* __restrict__ mEnc, int N) {
    __shared__ float red[4];
    int t = blockIdx.x * blockDim.x + threadIdx.x;
    int stride = gridDim.x * blockDim.x;
    float mx = -1e30f;
    for (int i = t; i < N; i += stride) mx = fmaxf(mx, logits[i]);
    #pragma unroll
    for (int off = 32; off; off >>= 1) mx = fmaxf(mx, __shfl_down(mx, off, 64));
    int lt = threadIdx.x;
    if ((lt & 63) == 0) red[lt >> 6] = mx;
    __syncthreads();
    if (lt == 0) {
        float m = red[0];
        for (int i = 1; i < (int)(blockDim.x >> 6); ++i) m = fmaxf(m, red[i]);
        atomicMax(mEnc, f2o(m));
    }
}

__global__ void k_exp(const float* __restrict__ logits,
                      const unsigned* __restrict__ mEnc,
                      float* __restrict__ att,
                      float* __restrict__ Z, int N) {
    __shared__ float red[4];
    float m = o2f(*mEnc);
    int t = blockIdx.x * blockDim.x + threadIdx.x;
    int stride = gridDim.x * blockDim.x;
    float s = 0.f;
    for (int i = t; i < N; i += stride) {
        float e = __expf(logits[i] - m);
        att[i] = e;
        s += e;
    }
    #pragma unroll
    for (int off = 32; off; off >>= 1) s += __shfl_down(s, off, 64);
    int lt = threadIdx.x;
    if ((lt & 63) == 0) red[lt >> 6] = s;
    __syncthreads();
    if (lt == 0) {
        float ss = 0.f;
        for (int i = 0; i < (int)(blockDim.x >> 6); ++i) ss += red[i];
        atomicAdd(Z, ss);
    }
}

// k_tail: MLP head; Ci scaled by 1/Z here (deferred softmax normalization).
__global__ void k_tail(const float* __restrict__ Ci,    // [256] (unnormalized)
                       const float* __restrict__ Z,     // [1]
                       const float* __restrict__ W1,    // [256][16]
                       const float* __restrict__ b1,    // [256]
                       const float* __restrict__ W2,    // [16]
                       const float* __restrict__ b2,    // [1]
                       const float* __restrict__ Wf,    // [64][256]
                       const float* __restrict__ bias,  // [64]
                       float* __restrict__ out) {       // [64]
    __shared__ float ci[256];
    __shared__ float fi2[256];
    int t = threadIdx.x;  // 256
    float invZ = 1.f / Z[0];
    ci[t] = Ci[t] * invZ;
    __syncthreads();

    float w1row[16];
    #pragma unroll
    for (int j = 0; j < 16; ++j) w1row[j] = W1[t * 16 + j];
    float bb = b1[t];
    float g = 0.f;
    #pragma unroll
    for (int i = 0; i < 16; ++i) {
        float s = bb;
        #pragma unroll
        for (int j = 0; j < 16; ++j) s = fmaf(ci[i * 16 + j], w1row[j], s);
        s = fmaxf(s, 0.f);
        float sg = 1.f / (1.f + __expf(-s));
        g = fmaf(sg, W2[i], g);
    }
    fi2[t] = fmaxf(g + b2[0], 0.f);
    __syncthreads();

    if (t < 64) {
        float s = bias[t];
        for (int f = 0; f < 256; ++f) s = fmaf(Wf[t * 256 + f], fi2[f], s);
        out[t] = s;
    }
}

// ---------------------------------------------------------------------------
// MAIN PATH (CSR gather; needs ~71 MB workspace)
// ---------------------------------------------------------------------------
__global__ void k_init(const float* __restrict__ Wc,
                       const float* __restrict__ alphaC,
                       const float* __restrict__ w,
                       float* __restrict__ M,
                       int* __restrict__ counts,     // [N] -> 0
                       float* __restrict__ Ci,
                       float* __restrict__ Z,
                       unsigned* __restrict__ mEnc,
                       int N) {
    int t = blockIdx.x * blockDim.x + threadIdx.x;
    int stride = gridDim.x * blockDim.x;
    for (int i = t; i < N; i += stride) counts[i] = 0;
    if (blockIdx.x == 0) {
        __shared__ float wWc[16];
        int tt = threadIdx.x;  // 256
        if (tt < 16) {
            float s = 0.f;
            for (int o = 0; o < 64; ++o) s = fmaf(w[o], Wc[o * 16 + tt], s);
            wWc[tt] = s;
        }
        __syncthreads();
        M[tt]  = wWc[tt >> 4] * alphaC[tt & 15];
        Ci[tt] = 0.f;
        if (tt == 0) { Z[0] = 0.f; mEnc[0] = 0u; }
    }
}

// k_build: bucketed CSR. One atomic + one 4B scatter write per edge.
__global__ void k_build(const int* __restrict__ dst,
                        int* __restrict__ counts,
                        int* __restrict__ eidx,   // [N*CAP]
                        int E) {
    int t = blockIdx.x * blockDim.x + threadIdx.x;
    int stride = gridDim.x * blockDim.x;
    for (int e = t; e < E; e += stride) {
        int d = dst[e];
        int pos = atomicAdd(&counts[d], 1);
        if (pos < CAP) eidx[d * CAP + pos] = e;
    }
}

// k_nodes: one 256-thread block per node. Gather the node's edge matrices
// (coalesced 1 KB granules), accumulate corr_n in registers (thread t owns
// element t), write corr_n, and compute logit_n = dot(M, corr_n) in-block.
// Single pass over the 1.024 GB Cijj tensor. No logit atomics.
__global__ void k_nodes(const float* __restrict__ Sij,
                        const float* __restrict__ C,      // [E*256]
                        const int* __restrict__ counts,
                        const int* __restrict__ eidx,
                        const float* __restrict__ M,      // [256]
                        float* __restrict__ corr,         // [N*256]
                        float* __restrict__ logits) {     // [N]
    int n = blockIdx.x;
    int t = threadIdx.x;  // 256
    int cnt = counts[n];
    if (cnt > CAP) cnt = CAP;

    __shared__ int   se[CAP];
    __shared__ float sw[CAP];
    if (t < cnt) {
        int e = eidx[n * CAP + t];
        se[t] = e;
        sw[t] = Sij[e];
    }
    __syncthreads();

    float a0 = 0.f, a1 = 0.f, a2 = 0.f, a3 = 0.f;
    int i = 0;
    for (; i + 4 <= cnt; i += 4) {   // 4 independent loads in flight
        size_t b0 = ((size_t)se[i])     << 8;
        size_t b1 = ((size_t)se[i + 1]) << 8;
        size_t b2 = ((size_t)se[i + 2]) << 8;
        size_t b3 = ((size_t)se[i + 3]) << 8;
        float c0 = __builtin_nontemporal_load(C + b0 + t);
        float c1 = __builtin_nontemporal_load(C + b1 + t);
        float c2 = __builtin_nontemporal_load(C + b2 + t);
        float c3 = __builtin_nontemporal_load(C + b3 + t);
        a0 = fmaf(sw[i],     c0, a0);
        a1 = fmaf(sw[i + 1], c1, a1);
        a2 = fmaf(sw[i + 2], c2, a2);
        a3 = fmaf(sw[i + 3], c3, a3);
    }
    for (; i < cnt; ++i) {
        float c = __builtin_nontemporal_load(C + (((size_t)se[i]) << 8) + t);
        a0 = fmaf(sw[i], c, a0);
    }
    float acc = (a0 + a1) + (a2 + a3);
    corr[(size_t)n * 256 + t] = acc;

    // logit_n = sum_t acc_t * M_t
    float s = acc * M[t];
    #pragma unroll
    for (int off = 32; off; off >>= 1) s += __shfl_down(s, off, 64);
    __shared__ float red[4];
    if ((t & 63) == 0) red[t >> 6] = s;
    __syncthreads();
    if (t == 0) logits[n] = red[0] + red[1] + red[2] + red[3];
}

// k_ci2: Ci[t] = sum_n att[n] * corr[n][t]  (att unnormalized; /Z in tail).
__global__ void k_ci2(const float* __restrict__ corr,
                      const float* __restrict__ att,
                      float* __restrict__ Ci, int N) {
    int t = threadIdx.x;  // 256
    int chunk = (N + gridDim.x - 1) / gridDim.x;
    int n0 = blockIdx.x * chunk;
    int n1 = n0 + chunk; if (n1 > N) n1 = N;
    float a0 = 0.f, a1 = 0.f;
    int n = n0;
    for (; n + 2 <= n1; n += 2) {
        a0 = fmaf(att[n],     corr[(size_t)n * 256 + t],       a0);
        a1 = fmaf(att[n + 1], corr[(size_t)(n + 1) * 256 + t], a1);
    }
    if (n < n1) a0 = fmaf(att[n], corr[(size_t)n * 256 + t], a0);
    atomicAdd(&Ci[t], a0 + a1);
}

// ---------------------------------------------------------------------------
// FALLBACK PATH (two streaming passes; ~0.4 MB workspace) — round-3 scheme.
// ---------------------------------------------------------------------------
__global__ void k_init_fb(const float* __restrict__ Wc,
                          const float* __restrict__ alphaC,
                          const float* __restrict__ w,
                          float* __restrict__ M,
                          float* __restrict__ logits,
                          float* __restrict__ Ci,
                          float* __restrict__ Z,
                          unsigned* __restrict__ mEnc,
                          int N) {
    int t = blockIdx.x * blockDim.x + threadIdx.x;
    int stride = gridDim.x * blockDim.x;
    for (int i = t; i < N; i += stride) logits[i] = 0.f;
    if (blockIdx.x == 0) {
        __shared__ float wWc[16];
        int tt = threadIdx.x;
        if (tt < 16) {
            float s = 0.f;
            for (int o = 0; o < 64; ++o) s = fmaf(w[o], Wc[o * 16 + tt], s);
            wWc[tt] = s;
        }
        __syncthreads();
        M[tt]  = wWc[tt >> 4] * alphaC[tt & 15];
        Ci[tt] = 0.f;
        if (tt == 0) { Z[0] = 0.f; mEnc[0] = 0u; }
    }
}

__global__ void k_logits_stream(const float* __restrict__ Sij,
                                const f32x4* __restrict__ C,
                                const int* __restrict__ dst,
                                const float* __restrict__ M,
                                float* __restrict__ logits,
                                int E) {
    int t = blockIdx.x * blockDim.x + threadIdx.x;
    int lane = t & 63;
    int sub  = lane >> 4;
    int eoff = lane & 15;
    int gwid  = t >> 6;
    int waves = (gridDim.x * blockDim.x) >> 6;

    const f32x4* M4 = reinterpret_cast<const f32x4*>(M);
    f32x4 m0 = M4[eoff], m1 = M4[16 + eoff], m2 = M4[32 + eoff], m3 = M4[48 + eoff];

    int nq = (E + 3) >> 2;
    for (int q = gwid; q < nq; q += waves) {
        int e = (q << 2) + sub;
        float d = 0.f;
        if (e < E) {
            size_t base = (size_t)e * 64 + eoff;
            f32x4 c0 = C[base];
            f32x4 c1 = C[base + 16];
            f32x4 c2 = C[base + 32];
            f32x4 c3 = C[base + 48];
            d = c0[0]*m0[0] + c0[1]*m0[1] + c0[2]*m0[2] + c0[3]*m0[3];
            d = fmaf(c1[0], m1[0], fmaf(c1[1], m1[1], fmaf(c1[2], m1[2], fmaf(c1[3], m1[3], d))));
            d = fmaf(c2[0], m2[0], fmaf(c2[1], m2[1], fmaf(c2[2], m2[2], fmaf(c2[3], m2[3], d))));
            d = fmaf(c3[0], m3[0], fmaf(c3[1], m3[1], fmaf(c3[2], m3[2], fmaf(c3[3], m3[3], d))));
        }
        #pragma unroll
        for (int off = 8; off; off >>= 1) d += __shfl_down(d, off, 16);
        if (eoff == 0 && e < E) atomicAdd(&logits[dst[e]], Sij[e] * d);
    }
}

__global__ void k_ci_stream(const float* __restrict__ Sij,
                            const f32x4* __restrict__ C,
                            const int* __restrict__ dst,
                            const float* __restrict__ att,
                            float* __restrict__ Ci,
                            int E) {
    int t = threadIdx.x;
    int lane = t & 63;
    int sub  = lane >> 4;
    int eoff = lane & 15;
    int gwid  = (blockIdx.x * blockDim.x + t) >> 6;
    int waves = (gridDim.x * blockDim.x) >> 6;

    f32x4 a0 = 0.f, a1 = 0.f, a2 = 0.f, a3 = 0.f;
    int nq = (E + 3) >> 2;
    for (int q = gwid; q < nq; q += waves) {
        int qq = nq - 1 - q;
        int e = (qq << 2) + sub;
        if (e < E) {
            float wgt = att[dst[e]] * Sij[e];
            size_t base = (size_t)e * 64 + eoff;
            f32x4 c0 = __builtin_nontemporal_load(C + base);
            f32x4 c1 = __builtin_nontemporal_load(C + base + 16);
            f32x4 c2 = __builtin_nontemporal_load(C + base + 32);
            f32x4 c3 = __builtin_nontemporal_load(C + base + 48);
            a0 += wgt * c0;
            a1 += wgt * c1;
            a2 += wgt * c2;
            a3 += wgt * c3;
        }
    }
    __shared__ f32x4 part[256][4];
    part[t][0] = a0;
    part[t][1] = a1;
    part[t][2] = a2;
    part[t][3] = a3;
    __syncthreads();
    int k  = t & 3;
    int f4 = t >> 2;
    int eo = f4 & 15;
    int j  = f4 >> 4;
    float s = 0.f;
    #pragma unroll
    for (int wv = 0; wv < 4; ++wv)
        #pragma unroll
        for (int sb = 0; sb < 4; ++sb)
            s += part[wv * 64 + sb * 16 + eo][j][k];
    atomicAdd(&Ci[t], s);
}

// ---------------------------------------------------------------------------
extern "C" void kernel_launch(void* const* d_in, const int* in_sizes, int n_in,
                              void* d_out, int out_size, void* d_ws, size_t ws_size,
                              hipStream_t stream) {
    const float* Sij    = (const float*)d_in[0];
    const float* Cijj   = (const float*)d_in[1];
    const int*   dst    = (const int*)d_in[2];
    // d_in[3] = N (device scalar; fixed at 50000)
    const float* Wc     = (const float*)d_in[4];
    const float* alphaC = (const float*)d_in[5];
    // d_in[6] = alphaf, d_in[7] = b : softmax-invariant constant -> unused
    const float* w_     = (const float*)d_in[8];
    const float* Wf     = (const float*)d_in[9];
    const float* bias   = (const float*)d_in[10];
    const float* W1     = (const float*)d_in[11];
    const float* b1     = (const float*)d_in[12];
    const float* W2     = (const float*)d_in[13];
    const float* b2     = (const float*)d_in[14];

    const int E = in_sizes[0];
    const int N = NNODES;

    // Main-path workspace: counts[N] | eidx[N*CAP] | corr[N*256] |
    //                      logits[N] | att[N] | M[256] | Ci[256] | Z | mEnc
    size_t need = (size_t)N * 4 + (size_t)N * CAP * 4 + (size_t)N * 256 * 4
                + (size_t)N * 4 * 2 + (256 + 256 + 2) * 4 + 64;

    if (ws_size >= need) {
        int*   counts = (int*)d_ws;
        int*   eidx   = counts + N;
        float* corr   = (float*)(eidx + (size_t)N * CAP);
        float* logits = corr + (size_t)N * 256;
        float* att    = logits + N;
        float* M      = att + N;
        float* Ci     = M + 256;
        float* Z      = Ci + 256;
        unsigned* mEnc = (unsigned*)(Z + 1);

        k_init <<<64, 256, 0, stream>>>(Wc, alphaC, w_, M, counts, Ci, Z, mEnc, N);
        k_build<<<2048, 256, 0, stream>>>(dst, counts, eidx, E);
        k_nodes<<<N, 256, 0, stream>>>(Sij, Cijj, counts, eidx, M, corr, logits);
        k_max  <<<50, 256, 0, stream>>>(logits, mEnc, N);
        k_exp  <<<50, 256, 0, stream>>>(logits, mEnc, att, Z, N);
        k_ci2  <<<256, 256, 0, stream>>>(corr, att, Ci, N);
        k_tail <<<1, 256, 0, stream>>>(Ci, Z, W1, b1, W2, b2, Wf, bias, (float*)d_out);
    } else {
        // Fallback: two streaming passes over Cijj.
        float* logits = (float*)d_ws;
        float* att    = logits + N;
        float* M      = att + N;
        float* Ci     = M + 256;
        float* Z      = Ci + 256;
        unsigned* mEnc = (unsigned*)(Z + 1);

        k_init_fb<<<64, 256, 0, stream>>>(Wc, alphaC, w_, M, logits, Ci, Z, mEnc, N);
        k_logits_stream<<<2048, 256, 0, stream>>>(Sij, (const f32x4*)Cijj, dst, M, logits, E);
        k_max<<<50, 256, 0, stream>>>(logits, mEnc, N);
        k_exp<<<50, 256, 0, stream>>>(logits, mEnc, att, Z, N);
        k_ci_stream<<<2048, 256, 0, stream>>>(Sij, (const f32x4*)Cijj, dst, att, Ci, E);
        k_tail<<<1, 256, 0, stream>>>(Ci, Z, W1, b1, W2, b2, Wf, bias, (float*)d_out);
    }
}

// Round 5
// 321.138 us; speedup vs baseline: 1.5631x; 1.0857x over previous
//
#include <hip/hip_runtime.h>
#include <hip/hip_bf16.h>

// Problem constants (fixed by the reference):
//   E = 1,000,000 edges, N = 50,000 nodes, D = 16, OUT = 64, FDIM = 256.
// Output P is [1, 64] fp32.
//
// Algebra:
//   logits_n = dot(M, corr_n),  M = outer(w@Wc, alphaC)
//   (Wf@alphaf+b term is node-independent -> softmax-invariant -> dropped)
//   corr_n = sum_{e: dst(e)=n} Sij[e]*Cijj[e]
//   Ci = (1/Z) * sum_n exp(logit_n - m) * corr_n
// Main path: bucketed CSR -> per-node gather materializes corr (51.2 MB)
// -> Cijj (1.024 GB) read ONCE, via wave-per-granule float4 loads.
// 1/Z folded into the MLP tail. Fallback (small ws): two streaming passes.

#define NNODES 50000
#define CAP 96   // max edges/node; deg ~ Poisson(20), P(>96) astronomically small

typedef float f32x4 __attribute__((ext_vector_type(4)));

// Monotonic float<->uint encoding for atomicMax on signed floats.
__device__ __forceinline__ unsigned f2o(float f) {
    unsigned u = __float_as_uint(f);
    return (u & 0x80000000u) ? ~u : (u | 0x80000000u);
}
__device__ __forceinline__ float o2f(unsigned u) {
    return (u & 0x80000000u) ? __uint_as_float(u ^ 0x80000000u)
                             : __uint_as_float(~u);
}

// ---------------------------------------------------------------------------
// k_max: global max of logits -> mEnc.
// ---------------------------------------------------------------------------
__global__ void k_max(const float* __restrict__ logits,
                      unsigned* __restrict__ mEnc, int N) {
    __shared__ float red[4];
    int t = blockIdx.x * blockDim.x + threadIdx.x;
    int stride = gridDim.x * blockDim.x;
    float mx = -1e30f;
    for (int i = t; i < N; i += stride) mx = fmaxf(mx, logits[i]);
    #pragma unroll
    for (int off = 32; off; off >>= 1) mx = fmaxf(mx, __shfl_down(mx, off, 64));
    int lt = threadIdx.x;
    if ((lt & 63) == 0) red[lt >> 6] = mx;
    __syncthreads();
    if (lt == 0) {
        float m = red[0];
        for (int i = 1; i < (int)(blockDim.x >> 6); ++i) m = fmaxf(m, red[i]);
        atomicMax(mEnc, f2o(m));
    }
}

// ---------------------------------------------------------------------------
// k_tail: MLP head; Ci scaled by 1/Z here (deferred softmax normalization).
// ---------------------------------------------------------------------------
__global__ void k_tail(const float* __restrict__ Ci,    // [256] (unnormalized)
                       const float* __restrict__ Z,     // [1]
                       const float* __restrict__ W1,    // [256][16]
                       const float* __restrict__ b1,    // [256]
                       const float* __restrict__ W2,    // [16]
                       const float* __restrict__ b2,    // [1]
                       const float* __restrict__ Wf,    // [64][256]
                       const float* __restrict__ bias,  // [64]
                       float* __restrict__ out) {       // [64]
    __shared__ float ci[256];
    __shared__ float fi2[256];
    int t = threadIdx.x;  // 256
    float invZ = 1.f / Z[0];
    ci[t] = Ci[t] * invZ;
    __syncthreads();

    float w1row[16];
    #pragma unroll
    for (int j = 0; j < 16; ++j) w1row[j] = W1[t * 16 + j];
    float bb = b1[t];
    float g = 0.f;
    #pragma unroll
    for (int i = 0; i < 16; ++i) {
        float s = bb;
        #pragma unroll
        for (int j = 0; j < 16; ++j) s = fmaf(ci[i * 16 + j], w1row[j], s);
        s = fmaxf(s, 0.f);
        float sg = 1.f / (1.f + __expf(-s));
        g = fmaf(sg, W2[i], g);
    }
    fi2[t] = fmaxf(g + b2[0], 0.f);
    __syncthreads();

    if (t < 64) {
        float s = bias[t];
        for (int f = 0; f < 256; ++f) s = fmaf(Wf[t * 256 + f], fi2[f], s);
        out[t] = s;
    }
}

// ---------------------------------------------------------------------------
// MAIN PATH
// ---------------------------------------------------------------------------
__global__ void k_init(const float* __restrict__ Wc,
                       const float* __restrict__ alphaC,
                       const float* __restrict__ w,
                       float* __restrict__ M,
                       int* __restrict__ counts,     // [N] -> 0
                       float* __restrict__ Ci,
                       float* __restrict__ Z,
                       unsigned* __restrict__ mEnc,
                       int N) {
    int t = blockIdx.x * blockDim.x + threadIdx.x;
    int stride = gridDim.x * blockDim.x;
    for (int i = t; i < N; i += stride) counts[i] = 0;
    if (blockIdx.x == 0) {
        __shared__ float wWc[16];
        int tt = threadIdx.x;  // 256
        if (tt < 16) {
            float s = 0.f;
            for (int o = 0; o < 64; ++o) s = fmaf(w[o], Wc[o * 16 + tt], s);
            wWc[tt] = s;
        }
        __syncthreads();
        M[tt]  = wWc[tt >> 4] * alphaC[tt & 15];
        Ci[tt] = 0.f;
        if (tt == 0) { Z[0] = 0.f; mEnc[0] = 0u; }
    }
}

// k_build: bucketed CSR. One atomic + one 4B scatter write per edge.
__global__ void k_build(const int* __restrict__ dst,
                        int* __restrict__ counts,
                        int* __restrict__ eidx,   // [N*CAP]
                        int E) {
    int t = blockIdx.x * blockDim.x + threadIdx.x;
    int stride = gridDim.x * blockDim.x;
    for (int e = t; e < E; e += stride) {
        int d = dst[e];
        int pos = atomicAdd(&counts[d], 1);
        if (pos < CAP) eidx[d * CAP + pos] = e;
    }
}

// k_nodes: one 256-thread block per node. Wave-per-granule float4 gather:
// wave w handles edges i = w, w+4, w+8, ... (2-deep unroll -> 8 independent
// 16B loads in flight per block). Lane l owns elements l*4..l*4+3 within its
// wave; cross-wave element reduce via LDS. Writes corr_n, computes logit_n.
__global__ void k_nodes(const float* __restrict__ Sij,
                        const f32x4* __restrict__ C4,     // [E*64]
                        const int* __restrict__ counts,
                        const int* __restrict__ eidx,
                        const float* __restrict__ M,      // [256]
                        float* __restrict__ corr,         // [N*256]
                        float* __restrict__ logits) {     // [N]
    int n = blockIdx.x;
    int t = threadIdx.x;  // 256
    int w = t >> 6;
    int l = t & 63;
    int cnt = counts[n];
    if (cnt > CAP) cnt = CAP;

    __shared__ int   se[CAP];
    __shared__ float sw[CAP];
    if (t < cnt) {
        int e = eidx[n * CAP + t];
        se[t] = e;
        sw[t] = Sij[e];
    }
    __syncthreads();

    f32x4 a0 = 0.f, a1 = 0.f;
    int i = w;
    for (; i + 4 < cnt; i += 8) {       // consume edges i and i+4
        size_t bA = ((size_t)se[i])     << 6;
        size_t bB = ((size_t)se[i + 4]) << 6;
        f32x4 cA = __builtin_nontemporal_load(C4 + bA + l);
        f32x4 cB = __builtin_nontemporal_load(C4 + bB + l);
        a0 += sw[i]     * cA;
        a1 += sw[i + 4] * cB;
    }
    if (i < cnt) {
        f32x4 c = __builtin_nontemporal_load(C4 + (((size_t)se[i]) << 6) + l);
        a0 += sw[i] * c;
    }
    f32x4 acc = a0 + a1;

    __shared__ f32x4 part[4][64];   // 4 KiB
    part[w][l] = acc;
    __syncthreads();
    // element t = ll*4 + kk  (ll = lane-within-wave, kk = f32x4 component)
    int ll = t >> 2, kk = t & 3;
    float s = part[0][ll][kk] + part[1][ll][kk] + part[2][ll][kk] + part[3][ll][kk];
    corr[(size_t)n * 256 + t] = s;

    // logit_n = sum_t s_t * M_t
    float d = s * M[t];
    #pragma unroll
    for (int off = 32; off; off >>= 1) d += __shfl_down(d, off, 64);
    __shared__ float red[4];
    if ((t & 63) == 0) red[t >> 6] = d;
    __syncthreads();
    if (t == 0) logits[n] = red[0] + red[1] + red[2] + red[3];
}

// k_wsum: fused exp + weighted corr sum.
//   att tile (256 nodes) computed into LDS; Ci[t] += sum_n att_n*corr[n][t];
//   Z += sum att  (one atomic per block).  att never hits global memory.
__global__ void k_wsum(const float* __restrict__ logits,
                       const unsigned* __restrict__ mEnc,
                       const float* __restrict__ corr,
                       float* __restrict__ Z,
                       float* __restrict__ Ci, int N) {
    __shared__ float satt[256];
    __shared__ float red[4];
    float m = o2f(*mEnc);
    int t = threadIdx.x;  // 256
    int chunk = (N + gridDim.x - 1) / gridDim.x;
    int n0 = blockIdx.x * chunk;
    int n1 = n0 + chunk; if (n1 > N) n1 = N;

    float zpart = 0.f;
    float a = 0.f;
    for (int base = n0; base < n1; base += 256) {
        int nn = n1 - base; if (nn > 256) nn = 256;
        float e = 0.f;
        if (t < nn) e = __expf(logits[base + t] - m);
        satt[t] = e;
        zpart += e;
        __syncthreads();
        int j = 0;
        for (; j + 4 <= nn; j += 4) {
            a = fmaf(satt[j],     corr[(size_t)(base + j)     * 256 + t], a);
            a = fmaf(satt[j + 1], corr[(size_t)(base + j + 1) * 256 + t], a);
            a = fmaf(satt[j + 2], corr[(size_t)(base + j + 2) * 256 + t], a);
            a = fmaf(satt[j + 3], corr[(size_t)(base + j + 3) * 256 + t], a);
        }
        for (; j < nn; ++j)
            a = fmaf(satt[j], corr[(size_t)(base + j) * 256 + t], a);
        __syncthreads();
    }
    atomicAdd(&Ci[t], a);

    #pragma unroll
    for (int off = 32; off; off >>= 1) zpart += __shfl_down(zpart, off, 64);
    if ((t & 63) == 0) red[t >> 6] = zpart;
    __syncthreads();
    if (t == 0) atomicAdd(Z, red[0] + red[1] + red[2] + red[3]);
}

// ---------------------------------------------------------------------------
// FALLBACK PATH (two streaming passes; ~0.4 MB workspace)
// ---------------------------------------------------------------------------
__global__ void k_init_fb(const float* __restrict__ Wc,
                          const float* __restrict__ alphaC,
                          const float* __restrict__ w,
                          float* __restrict__ M,
                          float* __restrict__ logits,
                          float* __restrict__ Ci,
                          float* __restrict__ Z,
                          unsigned* __restrict__ mEnc,
                          int N) {
    int t = blockIdx.x * blockDim.x + threadIdx.x;
    int stride = gridDim.x * blockDim.x;
    for (int i = t; i < N; i += stride) logits[i] = 0.f;
    if (blockIdx.x == 0) {
        __shared__ float wWc[16];
        int tt = threadIdx.x;
        if (tt < 16) {
            float s = 0.f;
            for (int o = 0; o < 64; ++o) s = fmaf(w[o], Wc[o * 16 + tt], s);
            wWc[tt] = s;
        }
        __syncthreads();
        M[tt]  = wWc[tt >> 4] * alphaC[tt & 15];
        Ci[tt] = 0.f;
        if (tt == 0) { Z[0] = 0.f; mEnc[0] = 0u; }
    }
}

__global__ void k_exp_fb(const float* __restrict__ logits,
                         const unsigned* __restrict__ mEnc,
                         float* __restrict__ att,
                         float* __restrict__ Z, int N) {
    __shared__ float red[4];
    float m = o2f(*mEnc);
    int t = blockIdx.x * blockDim.x + threadIdx.x;
    int stride = gridDim.x * blockDim.x;
    float s = 0.f;
    for (int i = t; i < N; i += stride) {
        float e = __expf(logits[i] - m);
        att[i] = e;
        s += e;
    }
    #pragma unroll
    for (int off = 32; off; off >>= 1) s += __shfl_down(s, off, 64);
    int lt = threadIdx.x;
    if ((lt & 63) == 0) red[lt >> 6] = s;
    __syncthreads();
    if (lt == 0) {
        float ss = 0.f;
        for (int i = 0; i < (int)(blockDim.x >> 6); ++i) ss += red[i];
        atomicAdd(Z, ss);
    }
}

__global__ void k_logits_stream(const float* __restrict__ Sij,
                                const f32x4* __restrict__ C,
                                const int* __restrict__ dst,
                                const float* __restrict__ M,
                                float* __restrict__ logits,
                                int E) {
    int t = blockIdx.x * blockDim.x + threadIdx.x;
    int lane = t & 63;
    int sub  = lane >> 4;
    int eoff = lane & 15;
    int gwid  = t >> 6;
    int waves = (gridDim.x * blockDim.x) >> 6;

    const f32x4* M4 = reinterpret_cast<const f32x4*>(M);
    f32x4 m0 = M4[eoff], m1 = M4[16 + eoff], m2 = M4[32 + eoff], m3 = M4[48 + eoff];

    int nq = (E + 3) >> 2;
    for (int q = gwid; q < nq; q += waves) {
        int e = (q << 2) + sub;
        float d = 0.f;
        if (e < E) {
            size_t base = (size_t)e * 64 + eoff;
            f32x4 c0 = C[base];
            f32x4 c1 = C[base + 16];
            f32x4 c2 = C[base + 32];
            f32x4 c3 = C[base + 48];
            d = c0[0]*m0[0] + c0[1]*m0[1] + c0[2]*m0[2] + c0[3]*m0[3];
            d = fmaf(c1[0], m1[0], fmaf(c1[1], m1[1], fmaf(c1[2], m1[2], fmaf(c1[3], m1[3], d))));
            d = fmaf(c2[0], m2[0], fmaf(c2[1], m2[1], fmaf(c2[2], m2[2], fmaf(c2[3], m2[3], d))));
            d = fmaf(c3[0], m3[0], fmaf(c3[1], m3[1], fmaf(c3[2], m3[2], fmaf(c3[3], m3[3], d))));
        }
        #pragma unroll
        for (int off = 8; off; off >>= 1) d += __shfl_down(d, off, 16);
        if (eoff == 0 && e < E) atomicAdd(&logits[dst[e]], Sij[e] * d);
    }
}

__global__ void k_ci_stream(const float* __restrict__ Sij,
                            const f32x4* __restrict__ C,
                            const int* __restrict__ dst,
                            const float* __restrict__ att,
                            float* __restrict__ Ci,
                            int E) {
    int t = threadIdx.x;
    int lane = t & 63;
    int sub  = lane >> 4;
    int eoff = lane & 15;
    int gwid  = (blockIdx.x * blockDim.x + t) >> 6;
    int waves = (gridDim.x * blockDim.x) >> 6;

    f32x4 a0 = 0.f, a1 = 0.f, a2 = 0.f, a3 = 0.f;
    int nq = (E + 3) >> 2;
    for (int q = gwid; q < nq; q += waves) {
        int qq = nq - 1 - q;
        int e = (qq << 2) + sub;
        if (e < E) {
            float wgt = att[dst[e]] * Sij[e];
            size_t base = (size_t)e * 64 + eoff;
            f32x4 c0 = __builtin_nontemporal_load(C + base);
            f32x4 c1 = __builtin_nontemporal_load(C + base + 16);
            f32x4 c2 = __builtin_nontemporal_load(C + base + 32);
            f32x4 c3 = __builtin_nontemporal_load(C + base + 48);
            a0 += wgt * c0;
            a1 += wgt * c1;
            a2 += wgt * c2;
            a3 += wgt * c3;
        }
    }
    __shared__ f32x4 part[256][4];
    part[t][0] = a0;
    part[t][1] = a1;
    part[t][2] = a2;
    part[t][3] = a3;
    __syncthreads();
    int k  = t & 3;
    int f4 = t >> 2;
    int eo = f4 & 15;
    int j  = f4 >> 4;
    float s = 0.f;
    #pragma unroll
    for (int wv = 0; wv < 4; ++wv)
        #pragma unroll
        for (int sb = 0; sb < 4; ++sb)
            s += part[wv * 64 + sb * 16 + eo][j][k];
    atomicAdd(&Ci[t], s);
}

// ---------------------------------------------------------------------------
extern "C" void kernel_launch(void* const* d_in, const int* in_sizes, int n_in,
                              void* d_out, int out_size, void* d_ws, size_t ws_size,
                              hipStream_t stream) {
    const float* Sij    = (const float*)d_in[0];
    const float* Cijj   = (const float*)d_in[1];
    const int*   dst    = (const int*)d_in[2];
    // d_in[3] = N (device scalar; fixed at 50000)
    const float* Wc     = (const float*)d_in[4];
    const float* alphaC = (const float*)d_in[5];
    // d_in[6] = alphaf, d_in[7] = b : softmax-invariant constant -> unused
    const float* w_     = (const float*)d_in[8];
    const float* Wf     = (const float*)d_in[9];
    const float* bias   = (const float*)d_in[10];
    const float* W1     = (const float*)d_in[11];
    const float* b1     = (const float*)d_in[12];
    const float* W2     = (const float*)d_in[13];
    const float* b2     = (const float*)d_in[14];

    const int E = in_sizes[0];
    const int N = NNODES;

    // Main-path workspace: counts[N] | eidx[N*CAP] | corr[N*256] |
    //                      logits[N] | M[256] | Ci[256] | Z | mEnc
    size_t need = (size_t)N * 4 + (size_t)N * CAP * 4 + (size_t)N * 256 * 4
                + (size_t)N * 4 + (256 + 256 + 2) * 4 + 64;

    if (ws_size >= need) {
        int*   counts = (int*)d_ws;
        int*   eidx   = counts + N;
        float* corr   = (float*)(eidx + (size_t)N * CAP);
        float* logits = corr + (size_t)N * 256;
        float* M      = logits + N;
        float* Ci     = M + 256;
        float* Z      = Ci + 256;
        unsigned* mEnc = (unsigned*)(Z + 1);

        k_init <<<64, 256, 0, stream>>>(Wc, alphaC, w_, M, counts, Ci, Z, mEnc, N);
        k_build<<<2048, 256, 0, stream>>>(dst, counts, eidx, E);
        k_nodes<<<N, 256, 0, stream>>>(Sij, (const f32x4*)Cijj, counts, eidx, M,
                                       corr, logits);
        k_max  <<<50, 256, 0, stream>>>(logits, mEnc, N);
        k_wsum <<<256, 256, 0, stream>>>(logits, mEnc, corr, Z, Ci, N);
        k_tail <<<1, 256, 0, stream>>>(Ci, Z, W1, b1, W2, b2, Wf, bias, (float*)d_out);
    } else {
        // Fallback: two streaming passes over Cijj.
        float* logits = (float*)d_ws;
        float* att    = logits + N;
        float* M      = att + N;
        float* Ci     = M + 256;
        float* Z      = Ci + 256;
        unsigned* mEnc = (unsigned*)(Z + 1);

        k_init_fb<<<64, 256, 0, stream>>>(Wc, alphaC, w_, M, logits, Ci, Z, mEnc, N);
        k_logits_stream<<<2048, 256, 0, stream>>>(Sij, (const f32x4*)Cijj, dst, M, logits, E);
        k_max<<<50, 256, 0, stream>>>(logits, mEnc, N);
        k_exp_fb<<<50, 256, 0, stream>>>(logits, mEnc, att, Z, N);
        k_ci_stream<<<2048, 256, 0, stream>>>(Sij, (const f32x4*)Cijj, dst, att, Ci, E);
        k_tail<<<1, 256, 0, stream>>>(Ci, Z, W1, b1, W2, b2, Wf, bias, (float*)d_out);
    }
}

// Round 6
// 309.911 us; speedup vs baseline: 1.6197x; 1.0362x over previous
//
#include <hip/hip_runtime.h>
#include <hip/hip_bf16.h>

// Problem constants (fixed by the reference):
//   E = 1,000,000 edges, N = 50,000 nodes, D = 16, OUT = 64, FDIM = 256.
// Output P is [1, 64] fp32.
//
// Algebra:
//   logits_n = dot(M, corr_n),  M = outer(w@Wc, alphaC)
//   (Wf@alphaf+b term is node-independent -> softmax-invariant -> dropped)
//   corr_n = sum_{e: dst(e)=n} Sij[e]*Cijj[e]
//   Ci = (1/Z) * sum_n exp(logit_n - m) * corr_n
// Main path: bucketed CSR -> wave-per-node gather materializes corr (51.2 MB)
// -> Cijj (1.024 GB) read ONCE. 1/Z folded into the MLP tail.
// Fallback (small ws): two streaming passes over Cijj.

#define NNODES 50000
#define CAP 64   // max edges/node; deg ~ Poisson(20), P(>64) ~ 1e-14

typedef float f32x4 __attribute__((ext_vector_type(4)));

// Monotonic float<->uint encoding for atomicMax on signed floats.
__device__ __forceinline__ unsigned f2o(float f) {
    unsigned u = __float_as_uint(f);
    return (u & 0x80000000u) ? ~u : (u | 0x80000000u);
}
__device__ __forceinline__ float o2f(unsigned u) {
    return (u & 0x80000000u) ? __uint_as_float(u ^ 0x80000000u)
                             : __uint_as_float(~u);
}

// ---------------------------------------------------------------------------
// k_max: global max of logits -> mEnc.
// ---------------------------------------------------------------------------
__global__ void k_max(const float* __restrict__ logits,
                      unsigned* __restrict__ mEnc, int N) {
    __shared__ float red[4];
    int t = blockIdx.x * blockDim.x + threadIdx.x;
    int stride = gridDim.x * blockDim.x;
    float mx = -1e30f;
    for (int i = t; i < N; i += stride) mx = fmaxf(mx, logits[i]);
    #pragma unroll
    for (int off = 32; off; off >>= 1) mx = fmaxf(mx, __shfl_down(mx, off, 64));
    int lt = threadIdx.x;
    if ((lt & 63) == 0) red[lt >> 6] = mx;
    __syncthreads();
    if (lt == 0) {
        float m = red[0];
        for (int i = 1; i < (int)(blockDim.x >> 6); ++i) m = fmaxf(m, red[i]);
        atomicMax(mEnc, f2o(m));
    }
}

// ---------------------------------------------------------------------------
// k_tail: MLP head; Ci scaled by 1/Z here (deferred softmax normalization).
// ---------------------------------------------------------------------------
__global__ void k_tail(const float* __restrict__ Ci,    // [256] (unnormalized)
                       const float* __restrict__ Z,     // [1]
                       const float* __restrict__ W1,    // [256][16]
                       const float* __restrict__ b1,    // [256]
                       const float* __restrict__ W2,    // [16]
                       const float* __restrict__ b2,    // [1]
                       const float* __restrict__ Wf,    // [64][256]
                       const float* __restrict__ bias,  // [64]
                       float* __restrict__ out) {       // [64]
    __shared__ float ci[256];
    __shared__ float fi2[256];
    int t = threadIdx.x;  // 256
    float invZ = 1.f / Z[0];
    ci[t] = Ci[t] * invZ;
    __syncthreads();

    float w1row[16];
    #pragma unroll
    for (int j = 0; j < 16; ++j) w1row[j] = W1[t * 16 + j];
    float bb = b1[t];
    float g = 0.f;
    #pragma unroll
    for (int i = 0; i < 16; ++i) {
        float s = bb;
        #pragma unroll
        for (int j = 0; j < 16; ++j) s = fmaf(ci[i * 16 + j], w1row[j], s);
        s = fmaxf(s, 0.f);
        float sg = 1.f / (1.f + __expf(-s));
        g = fmaf(sg, W2[i], g);
    }
    fi2[t] = fmaxf(g + b2[0], 0.f);
    __syncthreads();

    if (t < 64) {
        float s = bias[t];
        for (int f = 0; f < 256; ++f) s = fmaf(Wf[t * 256 + f], fi2[f], s);
        out[t] = s;
    }
}

// ---------------------------------------------------------------------------
// MAIN PATH
// ---------------------------------------------------------------------------
__global__ void k_init(const float* __restrict__ Wc,
                       const float* __restrict__ alphaC,
                       const float* __restrict__ w,
                       float* __restrict__ M,
                       int* __restrict__ counts,     // [N] -> 0
                       float* __restrict__ Ci,
                       float* __restrict__ Z,
                       unsigned* __restrict__ mEnc,
                       int N) {
    int t = blockIdx.x * blockDim.x + threadIdx.x;
    int stride = gridDim.x * blockDim.x;
    for (int i = t; i < N; i += stride) counts[i] = 0;
    if (blockIdx.x == 0) {
        __shared__ float wWc[16];
        int tt = threadIdx.x;  // 256
        if (tt < 16) {
            float s = 0.f;
            for (int o = 0; o < 64; ++o) s = fmaf(w[o], Wc[o * 16 + tt], s);
            wWc[tt] = s;
        }
        __syncthreads();
        M[tt]  = wWc[tt >> 4] * alphaC[tt & 15];
        Ci[tt] = 0.f;
        if (tt == 0) { Z[0] = 0.f; mEnc[0] = 0u; }
    }
}

// k_build: bucketed CSR. One atomic + one 4B scatter write per edge.
__global__ void k_build(const int* __restrict__ dst,
                        int* __restrict__ counts,
                        int* __restrict__ eidx,   // [N*CAP]
                        int E) {
    int t = blockIdx.x * blockDim.x + threadIdx.x;
    int stride = gridDim.x * blockDim.x;
    for (int e = t; e < E; e += stride) {
        int d = dst[e];
        int pos = atomicAdd(&counts[d], 1);
        if (pos < CAP) eidx[d * CAP + pos] = e;
    }
}

// k_nodes: ONE WAVE PER NODE (4 nodes / 256-block). Lane l owns elements
// 4l..4l+3 of the node's 256-element corr. The wave's edge list (<=64) is
// loaded once (coalesced eidx read + one Sij gather per lane) and broadcast
// via shfl. Gather loop is 4-deep unrolled: 4 independent 1 KB wave-loads
// in flight throughout. No LDS, no __syncthreads. Writes corr_n (f32x4,
// coalesced), computes logit_n via 6-step shuffle reduce.
__global__ void k_nodes(const float* __restrict__ Sij,
                        const f32x4* __restrict__ C4,     // [E*64]
                        const int* __restrict__ counts,
                        const int* __restrict__ eidx,
                        const float* __restrict__ M,      // [256]
                        float* __restrict__ corr,         // [N*256]
                        float* __restrict__ logits,       // [N]
                        int N) {
    int l = threadIdx.x & 63;
    int n = blockIdx.x * 4 + (threadIdx.x >> 6);
    if (n >= N) return;

    int cnt = counts[n];
    if (cnt > CAP) cnt = CAP;

    int   ev = 0;
    float sv = 0.f;
    if (l < cnt) {
        ev = eidx[n * CAP + l];   // coalesced
        sv = Sij[ev];             // one random 4B gather per lane
    }

    const f32x4* M4 = reinterpret_cast<const f32x4*>(M);
    f32x4 m = M4[l];

    f32x4 a0 = 0.f, a1 = 0.f, a2 = 0.f, a3 = 0.f;
    int i = 0;
    for (; i + 4 <= cnt; i += 4) {
        int e0 = __shfl(ev, i,     64);
        int e1 = __shfl(ev, i + 1, 64);
        int e2 = __shfl(ev, i + 2, 64);
        int e3 = __shfl(ev, i + 3, 64);
        float s0 = __shfl(sv, i,     64);
        float s1 = __shfl(sv, i + 1, 64);
        float s2 = __shfl(sv, i + 2, 64);
        float s3 = __shfl(sv, i + 3, 64);
        f32x4 c0 = __builtin_nontemporal_load(C4 + (((size_t)e0) << 6) + l);
        f32x4 c1 = __builtin_nontemporal_load(C4 + (((size_t)e1) << 6) + l);
        f32x4 c2 = __builtin_nontemporal_load(C4 + (((size_t)e2) << 6) + l);
        f32x4 c3 = __builtin_nontemporal_load(C4 + (((size_t)e3) << 6) + l);
        a0 += s0 * c0;
        a1 += s1 * c1;
        a2 += s2 * c2;
        a3 += s3 * c3;
    }
    for (; i < cnt; ++i) {
        int e = __shfl(ev, i, 64);
        float s = __shfl(sv, i, 64);
        f32x4 c = __builtin_nontemporal_load(C4 + (((size_t)e) << 6) + l);
        a0 += s * c;
    }
    f32x4 acc = (a0 + a1) + (a2 + a3);

    reinterpret_cast<f32x4*>(corr)[(size_t)n * 64 + l] = acc;  // coalesced 1 KB

    // logit_n = sum over 256 elements of acc*M
    float d = fmaf(acc[0], m[0], fmaf(acc[1], m[1],
              fmaf(acc[2], m[2], acc[3] * m[3])));
    #pragma unroll
    for (int off = 32; off; off >>= 1) d += __shfl_down(d, off, 64);
    if (l == 0) logits[n] = d;
}

// k_wsum: fused exp + weighted corr sum.
__global__ void k_wsum(const float* __restrict__ logits,
                       const unsigned* __restrict__ mEnc,
                       const float* __restrict__ corr,
                       float* __restrict__ Z,
                       float* __restrict__ Ci, int N) {
    __shared__ float satt[256];
    __shared__ float red[4];
    float m = o2f(*mEnc);
    int t = threadIdx.x;  // 256
    int chunk = (N + gridDim.x - 1) / gridDim.x;
    int n0 = blockIdx.x * chunk;
    int n1 = n0 + chunk; if (n1 > N) n1 = N;

    float zpart = 0.f;
    float a = 0.f;
    for (int base = n0; base < n1; base += 256) {
        int nn = n1 - base; if (nn > 256) nn = 256;
        float e = 0.f;
        if (t < nn) e = __expf(logits[base + t] - m);
        satt[t] = e;
        zpart += e;
        __syncthreads();
        int j = 0;
        for (; j + 4 <= nn; j += 4) {
            a = fmaf(satt[j],     corr[(size_t)(base + j)     * 256 + t], a);
            a = fmaf(satt[j + 1], corr[(size_t)(base + j + 1) * 256 + t], a);
            a = fmaf(satt[j + 2], corr[(size_t)(base + j + 2) * 256 + t], a);
            a = fmaf(satt[j + 3], corr[(size_t)(base + j + 3) * 256 + t], a);
        }
        for (; j < nn; ++j)
            a = fmaf(satt[j], corr[(size_t)(base + j) * 256 + t], a);
        __syncthreads();
    }
    atomicAdd(&Ci[t], a);

    #pragma unroll
    for (int off = 32; off; off >>= 1) zpart += __shfl_down(zpart, off, 64);
    if ((t & 63) == 0) red[t >> 6] = zpart;
    __syncthreads();
    if (t == 0) atomicAdd(Z, red[0] + red[1] + red[2] + red[3]);
}

// ---------------------------------------------------------------------------
// FALLBACK PATH (two streaming passes; ~0.4 MB workspace)
// ---------------------------------------------------------------------------
__global__ void k_init_fb(const float* __restrict__ Wc,
                          const float* __restrict__ alphaC,
                          const float* __restrict__ w,
                          float* __restrict__ M,
                          float* __restrict__ logits,
                          float* __restrict__ Ci,
                          float* __restrict__ Z,
                          unsigned* __restrict__ mEnc,
                          int N) {
    int t = blockIdx.x * blockDim.x + threadIdx.x;
    int stride = gridDim.x * blockDim.x;
    for (int i = t; i < N; i += stride) logits[i] = 0.f;
    if (blockIdx.x == 0) {
        __shared__ float wWc[16];
        int tt = threadIdx.x;
        if (tt < 16) {
            float s = 0.f;
            for (int o = 0; o < 64; ++o) s = fmaf(w[o], Wc[o * 16 + tt], s);
            wWc[tt] = s;
        }
        __syncthreads();
        M[tt]  = wWc[tt >> 4] * alphaC[tt & 15];
        Ci[tt] = 0.f;
        if (tt == 0) { Z[0] = 0.f; mEnc[0] = 0u; }
    }
}

__global__ void k_exp_fb(const float* __restrict__ logits,
                         const unsigned* __restrict__ mEnc,
                         float* __restrict__ att,
                         float* __restrict__ Z, int N) {
    __shared__ float red[4];
    float m = o2f(*mEnc);
    int t = blockIdx.x * blockDim.x + threadIdx.x;
    int stride = gridDim.x * blockDim.x;
    float s = 0.f;
    for (int i = t; i < N; i += stride) {
        float e = __expf(logits[i] - m);
        att[i] = e;
        s += e;
    }
    #pragma unroll
    for (int off = 32; off; off >>= 1) s += __shfl_down(s, off, 64);
    int lt = threadIdx.x;
    if ((lt & 63) == 0) red[lt >> 6] = s;
    __syncthreads();
    if (lt == 0) {
        float ss = 0.f;
        for (int i = 0; i < (int)(blockDim.x >> 6); ++i) ss += red[i];
        atomicAdd(Z, ss);
    }
}

__global__ void k_logits_stream(const float* __restrict__ Sij,
                                const f32x4* __restrict__ C,
                                const int* __restrict__ dst,
                                const float* __restrict__ M,
                                float* __restrict__ logits,
                                int E) {
    int t = blockIdx.x * blockDim.x + threadIdx.x;
    int lane = t & 63;
    int sub  = lane >> 4;
    int eoff = lane & 15;
    int gwid  = t >> 6;
    int waves = (gridDim.x * blockDim.x) >> 6;

    const f32x4* M4 = reinterpret_cast<const f32x4*>(M);
    f32x4 m0 = M4[eoff], m1 = M4[16 + eoff], m2 = M4[32 + eoff], m3 = M4[48 + eoff];

    int nq = (E + 3) >> 2;
    for (int q = gwid; q < nq; q += waves) {
        int e = (q << 2) + sub;
        float d = 0.f;
        if (e < E) {
            size_t base = (size_t)e * 64 + eoff;
            f32x4 c0 = C[base];
            f32x4 c1 = C[base + 16];
            f32x4 c2 = C[base + 32];
            f32x4 c3 = C[base + 48];
            d = c0[0]*m0[0] + c0[1]*m0[1] + c0[2]*m0[2] + c0[3]*m0[3];
            d = fmaf(c1[0], m1[0], fmaf(c1[1], m1[1], fmaf(c1[2], m1[2], fmaf(c1[3], m1[3], d))));
            d = fmaf(c2[0], m2[0], fmaf(c2[1], m2[1], fmaf(c2[2], m2[2], fmaf(c2[3], m2[3], d))));
            d = fmaf(c3[0], m3[0], fmaf(c3[1], m3[1], fmaf(c3[2], m3[2], fmaf(c3[3], m3[3], d))));
        }
        #pragma unroll
        for (int off = 8; off; off >>= 1) d += __shfl_down(d, off, 16);
        if (eoff == 0 && e < E) atomicAdd(&logits[dst[e]], Sij[e] * d);
    }
}

__global__ void k_ci_stream(const float* __restrict__ Sij,
                            const f32x4* __restrict__ C,
                            const int* __restrict__ dst,
                            const float* __restrict__ att,
                            float* __restrict__ Ci,
                            int E) {
    int t = threadIdx.x;
    int lane = t & 63;
    int sub  = lane >> 4;
    int eoff = lane & 15;
    int gwid  = (blockIdx.x * blockDim.x + t) >> 6;
    int waves = (gridDim.x * blockDim.x) >> 6;

    f32x4 a0 = 0.f, a1 = 0.f, a2 = 0.f, a3 = 0.f;
    int nq = (E + 3) >> 2;
    for (int q = gwid; q < nq; q += waves) {
        int qq = nq - 1 - q;
        int e = (qq << 2) + sub;
        if (e < E) {
            float wgt = att[dst[e]] * Sij[e];
            size_t base = (size_t)e * 64 + eoff;
            f32x4 c0 = __builtin_nontemporal_load(C + base);
            f32x4 c1 = __builtin_nontemporal_load(C + base + 16);
            f32x4 c2 = __builtin_nontemporal_load(C + base + 32);
            f32x4 c3 = __builtin_nontemporal_load(C + base + 48);
            a0 += wgt * c0;
            a1 += wgt * c1;
            a2 += wgt * c2;
            a3 += wgt * c3;
        }
    }
    __shared__ f32x4 part[256][4];
    part[t][0] = a0;
    part[t][1] = a1;
    part[t][2] = a2;
    part[t][3] = a3;
    __syncthreads();
    int k  = t & 3;
    int f4 = t >> 2;
    int eo = f4 & 15;
    int j  = f4 >> 4;
    float s = 0.f;
    #pragma unroll
    for (int wv = 0; wv < 4; ++wv)
        #pragma unroll
        for (int sb = 0; sb < 4; ++sb)
            s += part[wv * 64 + sb * 16 + eo][j][k];
    atomicAdd(&Ci[t], s);
}

// ---------------------------------------------------------------------------
extern "C" void kernel_launch(void* const* d_in, const int* in_sizes, int n_in,
                              void* d_out, int out_size, void* d_ws, size_t ws_size,
                              hipStream_t stream) {
    const float* Sij    = (const float*)d_in[0];
    const float* Cijj   = (const float*)d_in[1];
    const int*   dst    = (const int*)d_in[2];
    // d_in[3] = N (device scalar; fixed at 50000)
    const float* Wc     = (const float*)d_in[4];
    const float* alphaC = (const float*)d_in[5];
    // d_in[6] = alphaf, d_in[7] = b : softmax-invariant constant -> unused
    const float* w_     = (const float*)d_in[8];
    const float* Wf     = (const float*)d_in[9];
    const float* bias   = (const float*)d_in[10];
    const float* W1     = (const float*)d_in[11];
    const float* b1     = (const float*)d_in[12];
    const float* W2     = (const float*)d_in[13];
    const float* b2     = (const float*)d_in[14];

    const int E = in_sizes[0];
    const int N = NNODES;

    // Main-path workspace: counts[N] | eidx[N*CAP] | corr[N*256] |
    //                      logits[N] | M[256] | Ci[256] | Z | mEnc   (~64.5 MB)
    size_t need = (size_t)N * 4 + (size_t)N * CAP * 4 + (size_t)N * 256 * 4
                + (size_t)N * 4 + (256 + 256 + 2) * 4 + 64;

    if (ws_size >= need) {
        int*   counts = (int*)d_ws;
        int*   eidx   = counts + N;
        float* corr   = (float*)(eidx + (size_t)N * CAP);
        float* logits = corr + (size_t)N * 256;
        float* M      = logits + N;
        float* Ci     = M + 256;
        float* Z      = Ci + 256;
        unsigned* mEnc = (unsigned*)(Z + 1);

        k_init <<<64, 256, 0, stream>>>(Wc, alphaC, w_, M, counts, Ci, Z, mEnc, N);
        k_build<<<2048, 256, 0, stream>>>(dst, counts, eidx, E);
        k_nodes<<<(N + 3) / 4, 256, 0, stream>>>(Sij, (const f32x4*)Cijj, counts,
                                                 eidx, M, corr, logits, N);
        k_max  <<<50, 256, 0, stream>>>(logits, mEnc, N);
        k_wsum <<<256, 256, 0, stream>>>(logits, mEnc, corr, Z, Ci, N);
        k_tail <<<1, 256, 0, stream>>>(Ci, Z, W1, b1, W2, b2, Wf, bias, (float*)d_out);
    } else {
        // Fallback: two streaming passes over Cijj.
        float* logits = (float*)d_ws;
        float* att    = logits + N;
        float* M      = att + N;
        float* Ci     = M + 256;
        float* Z      = Ci + 256;
        unsigned* mEnc = (unsigned*)(Z + 1);

        k_init_fb<<<64, 256, 0, stream>>>(Wc, alphaC, w_, M, logits, Ci, Z, mEnc, N);
        k_logits_stream<<<2048, 256, 0, stream>>>(Sij, (const f32x4*)Cijj, dst, M, logits, E);
        k_max<<<50, 256, 0, stream>>>(logits, mEnc, N);
        k_exp_fb<<<50, 256, 0, stream>>>(logits, mEnc, att, Z, N);
        k_ci_stream<<<2048, 256, 0, stream>>>(Sij, (const f32x4*)Cijj, dst, att, Ci, E);
        k_tail<<<1, 256, 0, stream>>>(Ci, Z, W1, b1, W2, b2, Wf, bias, (float*)d_out);
    }
}